// Round 4
// baseline (3469.843 us; speedup 1.0000x reference)
//
#include <hip/hip_runtime.h>

#define NN 50000
#define EE 1600000

typedef __attribute__((ext_vector_type(8))) short bf16x8;
typedef __attribute__((ext_vector_type(8))) unsigned short u16x8;
typedef __attribute__((ext_vector_type(4))) float f32x4;

__device__ __forceinline__ float bf2f(unsigned short u) {
    union { unsigned int u; float f; } v; v.u = ((unsigned int)u) << 16; return v.f;
}
__device__ __forceinline__ unsigned short f2bf(float f) {
    union { float f; unsigned int u; } v; v.f = f;
    unsigned int x = v.u;
    x += ((x >> 16) & 1u) + 0x7FFFu;   // round-to-nearest-even
    return (unsigned short)(x >> 16);
}

// ------- transpose + hi/lo split: src fp32 [K][128] -> hi/lo bf16 [128][K] -------
__global__ void rg_transpose_split(const float* __restrict__ src,
                                   unsigned short* __restrict__ dhi,
                                   unsigned short* __restrict__ dlo,
                                   int total, int K) {
    int i = blockIdx.x * 256 + threadIdx.x;
    if (i >= total) return;
    int k = i >> 7;          // row in src
    int c = i & 127;         // col in src
    float v = src[i];
    unsigned short h = f2bf(v);
    dhi[c * K + k] = h;
    dlo[c * K + k] = f2bf(v - bf2f(h));
}

// ---------------- fused multimodal projection (fp32 in, fp32 out) ----------------
// x = sum_mod lrelu(feat_mod @ W_mod + b_mod)
__global__ __launch_bounds__(256) void rg_proj(
    const float* __restrict__ des, const float* __restrict__ twe,
    const float* __restrict__ num, const float* __restrict__ cat,
    const unsigned short* __restrict__ desHi, const unsigned short* __restrict__ desLo,
    const unsigned short* __restrict__ tweHi, const unsigned short* __restrict__ tweLo,
    const unsigned short* __restrict__ numHi, const unsigned short* __restrict__ numLo,
    const unsigned short* __restrict__ catHi, const unsigned short* __restrict__ catLo,
    const float* __restrict__ desB, const float* __restrict__ tweB,
    const float* __restrict__ numB, const float* __restrict__ catB,
    float* __restrict__ xf)
{
    __shared__ unsigned short Ahi[64 * 40];
    __shared__ unsigned short Alo[64 * 40];
    __shared__ unsigned short Bhi[128 * 40];
    __shared__ unsigned short Blo[128 * 40];

    const int tid = threadIdx.x;
    const int wave = tid >> 6, lane = tid & 63, q = lane >> 4, m15 = lane & 15;
    const int row0 = blockIdx.x * 64;

    const float* Aptr[4] = { des, twe, num, cat };
    const unsigned short* BHptr[4] = { desHi, tweHi, numHi, catHi };
    const unsigned short* BLptr[4] = { desLo, tweLo, numLo, catLo };
    const float* bptr[4] = { desB, tweB, numB, catB };
    const int Kmod[4] = { 768, 768, 5, 6 };

    float res[8][4];
#pragma unroll
    for (int t = 0; t < 8; ++t)
#pragma unroll
        for (int i = 0; i < 4; ++i) res[t][i] = 0.f;

    for (int mod = 0; mod < 4; ++mod) {
        const float* A = Aptr[mod];
        const unsigned short* BH = BHptr[mod];
        const unsigned short* BL = BLptr[mod];
        const int K = Kmod[mod];
        f32x4 acc[8];
#pragma unroll
        for (int t = 0; t < 8; ++t) acc[t] = (f32x4){0.f, 0.f, 0.f, 0.f};

        const int nsteps = (K + 31) >> 5;
        for (int ks = 0; ks < nsteps; ++ks) {
            const int k0 = ks << 5;
            __syncthreads();
            // A tile [64][32]: fp32 -> hi/lo bf16
            {
                const int r = tid >> 2, seg = tid & 3;
                const int gr = row0 + r;
                const int kb = k0 + seg * 8;
                u16x8 hi = {0,0,0,0,0,0,0,0}, lo = {0,0,0,0,0,0,0,0};
                if (gr < NN) {
                    const float* p = A + (long)gr * K + kb;
                    if (kb + 8 <= K) {
                        const f32x4 v0 = *(const f32x4*)p;
                        const f32x4 v1 = *(const f32x4*)(p + 4);
#pragma unroll
                        for (int j = 0; j < 4; ++j) {
                            unsigned short h0 = f2bf(v0[j]);
                            hi[j] = h0;  lo[j] = f2bf(v0[j] - bf2f(h0));
                            unsigned short h1 = f2bf(v1[j]);
                            hi[j+4] = h1; lo[j+4] = f2bf(v1[j] - bf2f(h1));
                        }
                    } else {
#pragma unroll
                        for (int j = 0; j < 8; ++j) {
                            const int k = kb + j;
                            if (k < K) {
                                float v = A[(long)gr * K + k];
                                unsigned short h = f2bf(v);
                                hi[j] = h; lo[j] = f2bf(v - bf2f(h));
                            }
                        }
                    }
                }
                *(u16x8*)(Ahi + r * 40 + seg * 8) = hi;
                *(u16x8*)(Alo + r * 40 + seg * 8) = lo;
            }
            // B tiles [128][32] from pre-split transposed weights
            {
                const int n = tid >> 1;
                const int base = (tid & 1) * 16;
#pragma unroll
                for (int h = 0; h < 2; ++h) {
                    const int kb = k0 + base + h * 8;
                    u16x8 vh = {0,0,0,0,0,0,0,0}, vl = {0,0,0,0,0,0,0,0};
                    if (kb + 8 <= K) {
                        vh = *(const u16x8*)(BH + (long)n * K + kb);
                        vl = *(const u16x8*)(BL + (long)n * K + kb);
                    } else {
#pragma unroll
                        for (int j = 0; j < 8; ++j) {
                            const int k = kb + j;
                            if (k < K) {
                                vh[j] = BH[(long)n * K + k];
                                vl[j] = BL[(long)n * K + k];
                            }
                        }
                    }
                    *(u16x8*)(Bhi + n * 40 + base + h * 8) = vh;
                    *(u16x8*)(Blo + n * 40 + base + h * 8) = vl;
                }
            }
            __syncthreads();
            const bf16x8 ah = *(const bf16x8*)(Ahi + (wave * 16 + m15) * 40 + q * 8);
            const bf16x8 al = *(const bf16x8*)(Alo + (wave * 16 + m15) * 40 + q * 8);
#pragma unroll
            for (int t = 0; t < 8; ++t) {
                const bf16x8 bh = *(const bf16x8*)(Bhi + ((t << 4) + m15) * 40 + q * 8);
                const bf16x8 bl = *(const bf16x8*)(Blo + ((t << 4) + m15) * 40 + q * 8);
                acc[t] = __builtin_amdgcn_mfma_f32_16x16x32_bf16(ah, bh, acc[t], 0, 0, 0);
                acc[t] = __builtin_amdgcn_mfma_f32_16x16x32_bf16(al, bh, acc[t], 0, 0, 0);
                acc[t] = __builtin_amdgcn_mfma_f32_16x16x32_bf16(ah, bl, acc[t], 0, 0, 0);
            }
        }
        // fold modality: lrelu(acc + bias), accumulate fp32
#pragma unroll
        for (int t = 0; t < 8; ++t) {
            const float bv = bptr[mod][(t << 4) + m15];
#pragma unroll
            for (int i = 0; i < 4; ++i) {
                const float v = acc[t][i] + bv;
                res[t][i] += (v > 0.f) ? v : 0.01f * v;
            }
        }
    }
#pragma unroll
    for (int t = 0; t < 8; ++t) {
        const int col = (t << 4) + m15;
#pragma unroll
        for (int i = 0; i < 4; ++i) {
            const int r = row0 + wave * 16 + q * 4 + i;
            if (r < NN) xf[(long)r * 128 + col] = res[t][i];
        }
    }
}

// ------- edge scatter: agg[r][dst][:] += x[src][:], cnt[r][dst] += 1 -------
__global__ void rg_scatter(const float* __restrict__ xf,
                           const int* __restrict__ ei, const int* __restrict__ et,
                           float* __restrict__ agg, float* __restrict__ cnt)
{
    const int lane = threadIdx.x & 63;
    const int gw = (blockIdx.x * blockDim.x + threadIdx.x) >> 6;
    const int nw = (gridDim.x * blockDim.x) >> 6;
    for (int e = gw; e < EE; e += nw) {
        const int src = ei[e];
        const int dst = ei[EE + e];
        const int r = et[e];
        const float2 v = *(const float2*)(xf + (long)src * 128 + lane * 2);
        float* base = agg + ((long)r * NN + dst) * 128 + lane * 2;
        __hip_atomic_fetch_add(base + 0, v.x, __ATOMIC_RELAXED, __HIP_MEMORY_SCOPE_AGENT);
        __hip_atomic_fetch_add(base + 1, v.y, __ATOMIC_RELAXED, __HIP_MEMORY_SCOPE_AGENT);
        if (lane == 0)
            __hip_atomic_fetch_add(cnt + (long)r * NN + dst, 1.0f, __ATOMIC_RELAXED,
                                   __HIP_MEMORY_SCOPE_AGENT);
    }
}

// ---------------- mean in place: agg[i] /= max(cnt,1) ----------------
__global__ void rg_mean(float* __restrict__ agg, const float* __restrict__ cnt, int total)
{
    const int i = blockIdx.x * 256 + threadIdx.x;
    if (i >= total) return;
    const float c = cnt[i >> 7];
    agg[i] = agg[i] / fmaxf(c, 1.0f);
}

// ------- fused multi-operand GEMM, fp32 A and fp32->split B (pre-split) -------
// out = act(sum_s A_s @ B_s + bias); A_s fp32 [NN][128]; B hi/lo TRANSPOSED bf16 [128][128].
// act: 0=lrelu, 1=relu. Output fp32.
__global__ __launch_bounds__(256) void rg_gemm(
    const float* __restrict__ A0, const float* __restrict__ A1,
    const float* __restrict__ A2,
    const unsigned short* __restrict__ B0h, const unsigned short* __restrict__ B0l,
    const unsigned short* __restrict__ B1h, const unsigned short* __restrict__ B1l,
    const unsigned short* __restrict__ B2h, const unsigned short* __restrict__ B2l,
    const float* __restrict__ bias, int S, int act,
    float* __restrict__ outf)
{
    __shared__ unsigned short Ahi[64 * 40];
    __shared__ unsigned short Alo[64 * 40];
    __shared__ unsigned short Bhi[128 * 40];
    __shared__ unsigned short Blo[128 * 40];

    const int tid = threadIdx.x;
    const int wave = tid >> 6, lane = tid & 63, q = lane >> 4, m15 = lane & 15;
    const int row0 = blockIdx.x * 64;

    const float* Aptr[3] = { A0, A1, A2 };
    const unsigned short* BHptr[3] = { B0h, B1h, B2h };
    const unsigned short* BLptr[3] = { B0l, B1l, B2l };

    f32x4 acc[8];
#pragma unroll
    for (int t = 0; t < 8; ++t) acc[t] = (f32x4){0.f, 0.f, 0.f, 0.f};

    for (int s = 0; s < S; ++s) {
        const float* A = Aptr[s];
        const unsigned short* BH = BHptr[s];
        const unsigned short* BL = BLptr[s];
#pragma unroll
        for (int ks = 0; ks < 4; ++ks) {
            const int k0 = ks << 5;
            __syncthreads();
            // A tile [64][32]: fp32 -> hi/lo
            {
                const int r = tid >> 2, seg = tid & 3;
                const int gr = row0 + r;
                u16x8 hi = {0,0,0,0,0,0,0,0}, lo = {0,0,0,0,0,0,0,0};
                if (gr < NN) {
                    const float* p = A + (long)gr * 128 + k0 + seg * 8;
                    const f32x4 v0 = *(const f32x4*)p;
                    const f32x4 v1 = *(const f32x4*)(p + 4);
#pragma unroll
                    for (int j = 0; j < 4; ++j) {
                        unsigned short h0 = f2bf(v0[j]);
                        hi[j] = h0;  lo[j] = f2bf(v0[j] - bf2f(h0));
                        unsigned short h1 = f2bf(v1[j]);
                        hi[j+4] = h1; lo[j+4] = f2bf(v1[j] - bf2f(h1));
                    }
                }
                *(u16x8*)(Ahi + r * 40 + seg * 8) = hi;
                *(u16x8*)(Alo + r * 40 + seg * 8) = lo;
            }
            // B hi/lo tiles [128][32]
            {
                const int n = tid >> 1;
                const int base = (tid & 1) * 16;
                *(u16x8*)(Bhi + n * 40 + base)     = *(const u16x8*)(BH + (long)n * 128 + k0 + base);
                *(u16x8*)(Bhi + n * 40 + base + 8) = *(const u16x8*)(BH + (long)n * 128 + k0 + base + 8);
                *(u16x8*)(Blo + n * 40 + base)     = *(const u16x8*)(BL + (long)n * 128 + k0 + base);
                *(u16x8*)(Blo + n * 40 + base + 8) = *(const u16x8*)(BL + (long)n * 128 + k0 + base + 8);
            }
            __syncthreads();
            const bf16x8 ah = *(const bf16x8*)(Ahi + (wave * 16 + m15) * 40 + q * 8);
            const bf16x8 al = *(const bf16x8*)(Alo + (wave * 16 + m15) * 40 + q * 8);
#pragma unroll
            for (int t = 0; t < 8; ++t) {
                const bf16x8 bh = *(const bf16x8*)(Bhi + ((t << 4) + m15) * 40 + q * 8);
                const bf16x8 bl = *(const bf16x8*)(Blo + ((t << 4) + m15) * 40 + q * 8);
                acc[t] = __builtin_amdgcn_mfma_f32_16x16x32_bf16(ah, bh, acc[t], 0, 0, 0);
                acc[t] = __builtin_amdgcn_mfma_f32_16x16x32_bf16(al, bh, acc[t], 0, 0, 0);
                acc[t] = __builtin_amdgcn_mfma_f32_16x16x32_bf16(ah, bl, acc[t], 0, 0, 0);
            }
        }
    }
#pragma unroll
    for (int t = 0; t < 8; ++t) {
        const int col = (t << 4) + m15;
        const float bv = bias[col];
#pragma unroll
        for (int i = 0; i < 4; ++i) {
            const int r = row0 + wave * 16 + q * 4 + i;
            if (r < NN) {
                float v = acc[t][i] + bv;
                v = act ? fmaxf(v, 0.f) : ((v > 0.f) ? v : 0.01f * v);
                outf[(long)r * 128 + col] = v;
            }
        }
    }
}

// ---------------- final 128->2 head: out = h @ w2 + b2 (all fp32) ----------------
__global__ void BotRGCN_64381559767213_kernel(const float* __restrict__ hf,
                                              const float* __restrict__ w2,
                                              const float* __restrict__ b2,
                                              float* __restrict__ out)
{
    const int lane = threadIdx.x & 63;
    const int gw = (blockIdx.x * blockDim.x + threadIdx.x) >> 6;
    const int nw = (gridDim.x * blockDim.x) >> 6;
    const int k2 = lane * 2;
    const float w00 = w2[k2 * 2 + 0], w01 = w2[k2 * 2 + 1];
    const float w10 = w2[k2 * 2 + 2], w11 = w2[k2 * 2 + 3];
    const float b0 = b2[0], b1 = b2[1];
    for (int n = gw; n < NN; n += nw) {
        const float2 v = *(const float2*)(hf + (long)n * 128 + k2);
        float p0 = v.x * w00 + v.y * w10;
        float p1 = v.x * w01 + v.y * w11;
#pragma unroll
        for (int off = 32; off > 0; off >>= 1) {
            p0 += __shfl_down(p0, off, 64);
            p1 += __shfl_down(p1, off, 64);
        }
        if (lane == 0) {
            *(float2*)(out + (long)n * 2) = make_float2(p0 + b0, p1 + b1);
        }
    }
}

extern "C" void kernel_launch(void* const* d_in, const int* in_sizes, int n_in,
                              void* d_out, int out_size, void* d_ws, size_t ws_size,
                              hipStream_t stream)
{
    const float* des    = (const float*)d_in[0];
    const float* twe    = (const float*)d_in[1];
    const float* num    = (const float*)d_in[2];
    const float* cat    = (const float*)d_in[3];
    const int*   ei     = (const int*)d_in[4];
    const int*   et     = (const int*)d_in[5];
    const float* des_w  = (const float*)d_in[6];
    const float* des_b  = (const float*)d_in[7];
    const float* twe_w  = (const float*)d_in[8];
    const float* twe_b  = (const float*)d_in[9];
    const float* num_w  = (const float*)d_in[10];
    const float* num_b  = (const float*)d_in[11];
    const float* cat_w  = (const float*)d_in[12];
    const float* cat_b  = (const float*)d_in[13];
    const float* rel_w  = (const float*)d_in[14];  // [2][2][128][128]
    const float* root_w = (const float*)d_in[15];  // [2][128][128]
    const float* rgcn_b = (const float*)d_in[16];  // [2][128]
    const float* mlp_w1 = (const float*)d_in[17];  // [128][128]
    const float* mlp_b1 = (const float*)d_in[18];
    const float* mlp_w2 = (const float*)d_in[19];  // [128][2]
    const float* mlp_b2 = (const float*)d_in[20];

    char* ws = (char*)d_ws;
    size_t off = 0;
    auto alloc = [&](size_t bytes) -> char* {
        char* p = ws + off;
        off += (bytes + 255) & ~(size_t)255;
        return p;
    };
    float* xf  = (float*)alloc((size_t)NN * 128 * 4);       // 25.6 MB
    float* agg = (float*)alloc((size_t)2 * NN * 128 * 4);   // 51.2 MB (doubles as h)
    float* cnt = (float*)alloc((size_t)2 * NN * 4);
    unsigned short* desHi = (unsigned short*)alloc((size_t)768 * 128 * 2);
    unsigned short* desLo = (unsigned short*)alloc((size_t)768 * 128 * 2);
    unsigned short* tweHi = (unsigned short*)alloc((size_t)768 * 128 * 2);
    unsigned short* tweLo = (unsigned short*)alloc((size_t)768 * 128 * 2);
    unsigned short* numHi = (unsigned short*)alloc((size_t)5 * 128 * 2);
    unsigned short* numLo = (unsigned short*)alloc((size_t)5 * 128 * 2);
    unsigned short* catHi = (unsigned short*)alloc((size_t)6 * 128 * 2);
    unsigned short* catLo = (unsigned short*)alloc((size_t)6 * 128 * 2);
    unsigned short* rootHi = (unsigned short*)alloc((size_t)2 * 16384 * 2);
    unsigned short* rootLo = (unsigned short*)alloc((size_t)2 * 16384 * 2);
    unsigned short* relHi  = (unsigned short*)alloc((size_t)4 * 16384 * 2);
    unsigned short* relLo  = (unsigned short*)alloc((size_t)4 * 16384 * 2);
    unsigned short* w1Hi   = (unsigned short*)alloc((size_t)16384 * 2);
    unsigned short* w1Lo   = (unsigned short*)alloc((size_t)16384 * 2);
    float* hf = agg;  // mean buffer dead once the MLP runs

    auto tr = [&](const float* s, unsigned short* dh, unsigned short* dl, int K) {
        const int total = K * 128;
        rg_transpose_split<<<(total + 255) / 256, 256, 0, stream>>>(s, dh, dl, total, K);
    };
    tr(des_w, desHi, desLo, 768);
    tr(twe_w, tweHi, tweLo, 768);
    tr(num_w, numHi, numLo, 5);
    tr(cat_w, catHi, catLo, 6);
    tr(root_w,         rootHi,         rootLo,         128);
    tr(root_w + 16384, rootHi + 16384, rootLo + 16384, 128);
    tr(rel_w + 0 * 16384, relHi + 0 * 16384, relLo + 0 * 16384, 128);
    tr(rel_w + 1 * 16384, relHi + 1 * 16384, relLo + 1 * 16384, 128);
    tr(rel_w + 2 * 16384, relHi + 2 * 16384, relLo + 2 * 16384, 128);
    tr(rel_w + 3 * 16384, relHi + 3 * 16384, relLo + 3 * 16384, 128);
    tr(mlp_w1, w1Hi, w1Lo, 128);

    const int gemm_grid = (NN + 63) / 64;  // 782
    rg_proj<<<gemm_grid, 256, 0, stream>>>(des, twe, num, cat,
                                           desHi, desLo, tweHi, tweLo,
                                           numHi, numLo, catHi, catLo,
                                           des_b, twe_b, num_b, cat_b, xf);

    for (int l = 0; l < 2; ++l) {
        hipMemsetAsync(agg, 0, (size_t)2 * NN * 128 * 4, stream);
        hipMemsetAsync(cnt, 0, (size_t)2 * NN * 4, stream);
        rg_scatter<<<2048, 256, 0, stream>>>(xf, ei, et, agg, cnt);
        rg_mean<<<(2 * NN * 128 + 255) / 256, 256, 0, stream>>>(agg, cnt, 2 * NN * 128);
        rg_gemm<<<gemm_grid, 256, 0, stream>>>(
            xf, agg, agg + (size_t)NN * 128,
            rootHi + (size_t)l * 16384, rootLo + (size_t)l * 16384,
            relHi + (size_t)(l * 2) * 16384, relLo + (size_t)(l * 2) * 16384,
            relHi + (size_t)(l * 2 + 1) * 16384, relLo + (size_t)(l * 2 + 1) * 16384,
            rgcn_b + l * 128, 3, 0, xf);
    }
    // MLP layer 1 (relu) -> hf (fp32)
    rg_gemm<<<gemm_grid, 256, 0, stream>>>(xf, nullptr, nullptr,
                                           w1Hi, w1Lo, nullptr, nullptr, nullptr, nullptr,
                                           mlp_b1, 1, 1, hf);
    // head (fp32 out)
    BotRGCN_64381559767213_kernel<<<2048, 256, 0, stream>>>(hf, mlp_w2, mlp_b2,
                                                            (float*)d_out);
}

// Round 5
// 1216.882 us; speedup vs baseline: 2.8514x; 2.8514x over previous
//
#include <hip/hip_runtime.h>

#define NN 50000
#define EE 1600000
#define NBINS (2 * NN)

typedef __attribute__((ext_vector_type(8))) short bf16x8;
typedef __attribute__((ext_vector_type(8))) unsigned short u16x8;
typedef __attribute__((ext_vector_type(4))) float f32x4;

__device__ __forceinline__ float bf2f(unsigned short u) {
    union { unsigned int u; float f; } v; v.u = ((unsigned int)u) << 16; return v.f;
}
__device__ __forceinline__ unsigned short f2bf(float f) {
    union { float f; unsigned int u; } v; v.f = f;
    unsigned int x = v.u;
    x += ((x >> 16) & 1u) + 0x7FFFu;   // round-to-nearest-even
    return (unsigned short)(x >> 16);
}

// ------- transpose + hi/lo split: src fp32 [K][128] -> hi/lo bf16 [128][K] -------
__global__ void rg_transpose_split(const float* __restrict__ src,
                                   unsigned short* __restrict__ dhi,
                                   unsigned short* __restrict__ dlo,
                                   int total, int K) {
    int i = blockIdx.x * 256 + threadIdx.x;
    if (i >= total) return;
    int k = i >> 7;
    int c = i & 127;
    float v = src[i];
    unsigned short h = f2bf(v);
    dhi[c * K + k] = h;
    dlo[c * K + k] = f2bf(v - bf2f(h));
}

// ---------------- edge counting sort (runs once per call, reused by both layers) ----------------
__global__ void rg_hist(const int* __restrict__ ei, const int* __restrict__ et,
                        int* __restrict__ hist) {
    int e = blockIdx.x * 256 + threadIdx.x;
    if (e >= EE) return;
    const int dst = ei[EE + e];
    const int r = et[e];
    atomicAdd(&hist[r * NN + dst], 1);
}

// exclusive prefix over NBINS bins; offs has NBINS+1 entries. Single 1024-thread block.
__global__ void rg_scan(const int* __restrict__ hist, int* __restrict__ offs) {
    __shared__ int lsum[1024];
    const int t = threadIdx.x;
    const int per = (NBINS + 1023) / 1024;   // 98
    const int base = t * per;
    int s = 0;
    for (int i = 0; i < per; ++i) {
        const int idx = base + i;
        if (idx < NBINS) s += hist[idx];
    }
    lsum[t] = s;
    __syncthreads();
    for (int d = 1; d < 1024; d <<= 1) {
        const int v = (t >= d) ? lsum[t - d] : 0;
        __syncthreads();
        lsum[t] += v;
        __syncthreads();
    }
    int run = (t == 0) ? 0 : lsum[t - 1];
    for (int i = 0; i < per; ++i) {
        const int idx = base + i;
        if (idx < NBINS) { offs[idx] = run; run += hist[idx]; }
    }
    if (t == 1023) offs[NBINS] = run;   // == EE
}

__global__ void rg_place(const int* __restrict__ ei, const int* __restrict__ et,
                         int* __restrict__ cursor, int* __restrict__ sorted_src) {
    int e = blockIdx.x * 256 + threadIdx.x;
    if (e >= EE) return;
    const int src = ei[e];
    const int dst = ei[EE + e];
    const int r = et[e];
    const int pos = atomicAdd(&cursor[r * NN + dst], 1);
    sorted_src[pos] = src;
}

// ------- atomic-free gather-reduce: agg[bin][:] = mean over sorted src rows -------
// one wave per bin; coalesced 512B row reads; streaming row write. Replaces scatter+memset+mean.
__global__ void rg_gather(const float* __restrict__ xf,
                          const int* __restrict__ sorted_src,
                          const int* __restrict__ offs,
                          float* __restrict__ agg) {
    const int lane = threadIdx.x & 63;
    const int gw = (blockIdx.x * blockDim.x + threadIdx.x) >> 6;
    const int nw = (gridDim.x * blockDim.x) >> 6;
    for (int bin = gw; bin < NBINS; bin += nw) {
        const int s = offs[bin], e = offs[bin + 1];
        float ax = 0.f, ay = 0.f;
        int i = s;
        for (; i + 1 < e; i += 2) {                 // 2-way unroll: two row loads in flight
            const int s0 = sorted_src[i];
            const int s1 = sorted_src[i + 1];
            const float2 v0 = *(const float2*)(xf + (long)s0 * 128 + lane * 2);
            const float2 v1 = *(const float2*)(xf + (long)s1 * 128 + lane * 2);
            ax += v0.x + v1.x;
            ay += v0.y + v1.y;
        }
        if (i < e) {
            const int s0 = sorted_src[i];
            const float2 v0 = *(const float2*)(xf + (long)s0 * 128 + lane * 2);
            ax += v0.x;
            ay += v0.y;
        }
        const float c = fmaxf((float)(e - s), 1.0f);
        *(float2*)(agg + (long)bin * 128 + lane * 2) = make_float2(ax / c, ay / c);
    }
}

// ---------------- fused multimodal projection (fp32 in, fp32 out) ----------------
__global__ __launch_bounds__(256) void rg_proj(
    const float* __restrict__ des, const float* __restrict__ twe,
    const float* __restrict__ num, const float* __restrict__ cat,
    const unsigned short* __restrict__ desHi, const unsigned short* __restrict__ desLo,
    const unsigned short* __restrict__ tweHi, const unsigned short* __restrict__ tweLo,
    const unsigned short* __restrict__ numHi, const unsigned short* __restrict__ numLo,
    const unsigned short* __restrict__ catHi, const unsigned short* __restrict__ catLo,
    const float* __restrict__ desB, const float* __restrict__ tweB,
    const float* __restrict__ numB, const float* __restrict__ catB,
    float* __restrict__ xf)
{
    __shared__ unsigned short Ahi[64 * 40];
    __shared__ unsigned short Alo[64 * 40];
    __shared__ unsigned short Bhi[128 * 40];
    __shared__ unsigned short Blo[128 * 40];

    const int tid = threadIdx.x;
    const int wave = tid >> 6, lane = tid & 63, q = lane >> 4, m15 = lane & 15;
    const int row0 = blockIdx.x * 64;

    const float* Aptr[4] = { des, twe, num, cat };
    const unsigned short* BHptr[4] = { desHi, tweHi, numHi, catHi };
    const unsigned short* BLptr[4] = { desLo, tweLo, numLo, catLo };
    const float* bptr[4] = { desB, tweB, numB, catB };
    const int Kmod[4] = { 768, 768, 5, 6 };

    float res[8][4];
#pragma unroll
    for (int t = 0; t < 8; ++t)
#pragma unroll
        for (int i = 0; i < 4; ++i) res[t][i] = 0.f;

    for (int mod = 0; mod < 4; ++mod) {
        const float* A = Aptr[mod];
        const unsigned short* BH = BHptr[mod];
        const unsigned short* BL = BLptr[mod];
        const int K = Kmod[mod];
        f32x4 acc[8];
#pragma unroll
        for (int t = 0; t < 8; ++t) acc[t] = (f32x4){0.f, 0.f, 0.f, 0.f};

        const int nsteps = (K + 31) >> 5;
        for (int ks = 0; ks < nsteps; ++ks) {
            const int k0 = ks << 5;
            __syncthreads();
            {
                const int r = tid >> 2, seg = tid & 3;
                const int gr = row0 + r;
                const int kb = k0 + seg * 8;
                u16x8 hi = {0,0,0,0,0,0,0,0}, lo = {0,0,0,0,0,0,0,0};
                if (gr < NN) {
                    const float* p = A + (long)gr * K + kb;
                    if (kb + 8 <= K) {
                        const f32x4 v0 = *(const f32x4*)p;
                        const f32x4 v1 = *(const f32x4*)(p + 4);
#pragma unroll
                        for (int j = 0; j < 4; ++j) {
                            unsigned short h0 = f2bf(v0[j]);
                            hi[j] = h0;  lo[j] = f2bf(v0[j] - bf2f(h0));
                            unsigned short h1 = f2bf(v1[j]);
                            hi[j+4] = h1; lo[j+4] = f2bf(v1[j] - bf2f(h1));
                        }
                    } else {
#pragma unroll
                        for (int j = 0; j < 8; ++j) {
                            const int k = kb + j;
                            if (k < K) {
                                float v = A[(long)gr * K + k];
                                unsigned short h = f2bf(v);
                                hi[j] = h; lo[j] = f2bf(v - bf2f(h));
                            }
                        }
                    }
                }
                *(u16x8*)(Ahi + r * 40 + seg * 8) = hi;
                *(u16x8*)(Alo + r * 40 + seg * 8) = lo;
            }
            {
                const int n = tid >> 1;
                const int base = (tid & 1) * 16;
#pragma unroll
                for (int h = 0; h < 2; ++h) {
                    const int kb = k0 + base + h * 8;
                    u16x8 vh = {0,0,0,0,0,0,0,0}, vl = {0,0,0,0,0,0,0,0};
                    if (kb + 8 <= K) {
                        vh = *(const u16x8*)(BH + (long)n * K + kb);
                        vl = *(const u16x8*)(BL + (long)n * K + kb);
                    } else {
#pragma unroll
                        for (int j = 0; j < 8; ++j) {
                            const int k = kb + j;
                            if (k < K) {
                                vh[j] = BH[(long)n * K + k];
                                vl[j] = BL[(long)n * K + k];
                            }
                        }
                    }
                    *(u16x8*)(Bhi + n * 40 + base + h * 8) = vh;
                    *(u16x8*)(Blo + n * 40 + base + h * 8) = vl;
                }
            }
            __syncthreads();
            const bf16x8 ah = *(const bf16x8*)(Ahi + (wave * 16 + m15) * 40 + q * 8);
            const bf16x8 al = *(const bf16x8*)(Alo + (wave * 16 + m15) * 40 + q * 8);
#pragma unroll
            for (int t = 0; t < 8; ++t) {
                const bf16x8 bh = *(const bf16x8*)(Bhi + ((t << 4) + m15) * 40 + q * 8);
                const bf16x8 bl = *(const bf16x8*)(Blo + ((t << 4) + m15) * 40 + q * 8);
                acc[t] = __builtin_amdgcn_mfma_f32_16x16x32_bf16(ah, bh, acc[t], 0, 0, 0);
                acc[t] = __builtin_amdgcn_mfma_f32_16x16x32_bf16(al, bh, acc[t], 0, 0, 0);
                acc[t] = __builtin_amdgcn_mfma_f32_16x16x32_bf16(ah, bl, acc[t], 0, 0, 0);
            }
        }
#pragma unroll
        for (int t = 0; t < 8; ++t) {
            const float bv = bptr[mod][(t << 4) + m15];
#pragma unroll
            for (int i = 0; i < 4; ++i) {
                const float v = acc[t][i] + bv;
                res[t][i] += (v > 0.f) ? v : 0.01f * v;
            }
        }
    }
#pragma unroll
    for (int t = 0; t < 8; ++t) {
        const int col = (t << 4) + m15;
#pragma unroll
        for (int i = 0; i < 4; ++i) {
            const int r = row0 + wave * 16 + q * 4 + i;
            if (r < NN) xf[(long)r * 128 + col] = res[t][i];
        }
    }
}

// ------- fused multi-operand GEMM, fp32 A on-the-fly split, pre-split B -------
__global__ __launch_bounds__(256) void rg_gemm(
    const float* __restrict__ A0, const float* __restrict__ A1,
    const float* __restrict__ A2,
    const unsigned short* __restrict__ B0h, const unsigned short* __restrict__ B0l,
    const unsigned short* __restrict__ B1h, const unsigned short* __restrict__ B1l,
    const unsigned short* __restrict__ B2h, const unsigned short* __restrict__ B2l,
    const float* __restrict__ bias, int S, int act,
    float* __restrict__ outf)
{
    __shared__ unsigned short Ahi[64 * 40];
    __shared__ unsigned short Alo[64 * 40];
    __shared__ unsigned short Bhi[128 * 40];
    __shared__ unsigned short Blo[128 * 40];

    const int tid = threadIdx.x;
    const int wave = tid >> 6, lane = tid & 63, q = lane >> 4, m15 = lane & 15;
    const int row0 = blockIdx.x * 64;

    const float* Aptr[3] = { A0, A1, A2 };
    const unsigned short* BHptr[3] = { B0h, B1h, B2h };
    const unsigned short* BLptr[3] = { B0l, B1l, B2l };

    f32x4 acc[8];
#pragma unroll
    for (int t = 0; t < 8; ++t) acc[t] = (f32x4){0.f, 0.f, 0.f, 0.f};

    for (int s = 0; s < S; ++s) {
        const float* A = Aptr[s];
        const unsigned short* BH = BHptr[s];
        const unsigned short* BL = BLptr[s];
#pragma unroll
        for (int ks = 0; ks < 4; ++ks) {
            const int k0 = ks << 5;
            __syncthreads();
            {
                const int r = tid >> 2, seg = tid & 3;
                const int gr = row0 + r;
                u16x8 hi = {0,0,0,0,0,0,0,0}, lo = {0,0,0,0,0,0,0,0};
                if (gr < NN) {
                    const float* p = A + (long)gr * 128 + k0 + seg * 8;
                    const f32x4 v0 = *(const f32x4*)p;
                    const f32x4 v1 = *(const f32x4*)(p + 4);
#pragma unroll
                    for (int j = 0; j < 4; ++j) {
                        unsigned short h0 = f2bf(v0[j]);
                        hi[j] = h0;  lo[j] = f2bf(v0[j] - bf2f(h0));
                        unsigned short h1 = f2bf(v1[j]);
                        hi[j+4] = h1; lo[j+4] = f2bf(v1[j] - bf2f(h1));
                    }
                }
                *(u16x8*)(Ahi + r * 40 + seg * 8) = hi;
                *(u16x8*)(Alo + r * 40 + seg * 8) = lo;
            }
            {
                const int n = tid >> 1;
                const int base = (tid & 1) * 16;
                *(u16x8*)(Bhi + n * 40 + base)     = *(const u16x8*)(BH + (long)n * 128 + k0 + base);
                *(u16x8*)(Bhi + n * 40 + base + 8) = *(const u16x8*)(BH + (long)n * 128 + k0 + base + 8);
                *(u16x8*)(Blo + n * 40 + base)     = *(const u16x8*)(BL + (long)n * 128 + k0 + base);
                *(u16x8*)(Blo + n * 40 + base + 8) = *(const u16x8*)(BL + (long)n * 128 + k0 + base + 8);
            }
            __syncthreads();
            const bf16x8 ah = *(const bf16x8*)(Ahi + (wave * 16 + m15) * 40 + q * 8);
            const bf16x8 al = *(const bf16x8*)(Alo + (wave * 16 + m15) * 40 + q * 8);
#pragma unroll
            for (int t = 0; t < 8; ++t) {
                const bf16x8 bh = *(const bf16x8*)(Bhi + ((t << 4) + m15) * 40 + q * 8);
                const bf16x8 bl = *(const bf16x8*)(Blo + ((t << 4) + m15) * 40 + q * 8);
                acc[t] = __builtin_amdgcn_mfma_f32_16x16x32_bf16(ah, bh, acc[t], 0, 0, 0);
                acc[t] = __builtin_amdgcn_mfma_f32_16x16x32_bf16(al, bh, acc[t], 0, 0, 0);
                acc[t] = __builtin_amdgcn_mfma_f32_16x16x32_bf16(ah, bl, acc[t], 0, 0, 0);
            }
        }
    }
#pragma unroll
    for (int t = 0; t < 8; ++t) {
        const int col = (t << 4) + m15;
        const float bv = bias[col];
#pragma unroll
        for (int i = 0; i < 4; ++i) {
            const int r = row0 + wave * 16 + q * 4 + i;
            if (r < NN) {
                float v = acc[t][i] + bv;
                v = act ? fmaxf(v, 0.f) : ((v > 0.f) ? v : 0.01f * v);
                outf[(long)r * 128 + col] = v;
            }
        }
    }
}

// ---------------- final 128->2 head ----------------
__global__ void BotRGCN_64381559767213_kernel(const float* __restrict__ hf,
                                              const float* __restrict__ w2,
                                              const float* __restrict__ b2,
                                              float* __restrict__ out)
{
    const int lane = threadIdx.x & 63;
    const int gw = (blockIdx.x * blockDim.x + threadIdx.x) >> 6;
    const int nw = (gridDim.x * blockDim.x) >> 6;
    const int k2 = lane * 2;
    const float w00 = w2[k2 * 2 + 0], w01 = w2[k2 * 2 + 1];
    const float w10 = w2[k2 * 2 + 2], w11 = w2[k2 * 2 + 3];
    const float b0 = b2[0], b1 = b2[1];
    for (int n = gw; n < NN; n += nw) {
        const float2 v = *(const float2*)(hf + (long)n * 128 + k2);
        float p0 = v.x * w00 + v.y * w10;
        float p1 = v.x * w01 + v.y * w11;
#pragma unroll
        for (int off = 32; off > 0; off >>= 1) {
            p0 += __shfl_down(p0, off, 64);
            p1 += __shfl_down(p1, off, 64);
        }
        if (lane == 0) {
            *(float2*)(out + (long)n * 2) = make_float2(p0 + b0, p1 + b1);
        }
    }
}

extern "C" void kernel_launch(void* const* d_in, const int* in_sizes, int n_in,
                              void* d_out, int out_size, void* d_ws, size_t ws_size,
                              hipStream_t stream)
{
    const float* des    = (const float*)d_in[0];
    const float* twe    = (const float*)d_in[1];
    const float* num    = (const float*)d_in[2];
    const float* cat    = (const float*)d_in[3];
    const int*   ei     = (const int*)d_in[4];
    const int*   et     = (const int*)d_in[5];
    const float* des_w  = (const float*)d_in[6];
    const float* des_b  = (const float*)d_in[7];
    const float* twe_w  = (const float*)d_in[8];
    const float* twe_b  = (const float*)d_in[9];
    const float* num_w  = (const float*)d_in[10];
    const float* num_b  = (const float*)d_in[11];
    const float* cat_w  = (const float*)d_in[12];
    const float* cat_b  = (const float*)d_in[13];
    const float* rel_w  = (const float*)d_in[14];
    const float* root_w = (const float*)d_in[15];
    const float* rgcn_b = (const float*)d_in[16];
    const float* mlp_w1 = (const float*)d_in[17];
    const float* mlp_b1 = (const float*)d_in[18];
    const float* mlp_w2 = (const float*)d_in[19];
    const float* mlp_b2 = (const float*)d_in[20];

    char* ws = (char*)d_ws;
    size_t off = 0;
    auto alloc = [&](size_t bytes) -> char* {
        char* p = ws + off;
        off += (bytes + 255) & ~(size_t)255;
        return p;
    };
    float* xf  = (float*)alloc((size_t)NN * 128 * 4);        // 25.6 MB
    float* agg = (float*)alloc((size_t)NBINS * 128 * 4);     // 51.2 MB (doubles as h)
    int* hist       = (int*)alloc((size_t)NBINS * 4);
    int* offs       = (int*)alloc((size_t)(NBINS + 1) * 4);
    int* cursor     = (int*)alloc((size_t)NBINS * 4);
    int* sorted_src = (int*)alloc((size_t)EE * 4);           // 6.4 MB
    unsigned short* desHi = (unsigned short*)alloc((size_t)768 * 128 * 2);
    unsigned short* desLo = (unsigned short*)alloc((size_t)768 * 128 * 2);
    unsigned short* tweHi = (unsigned short*)alloc((size_t)768 * 128 * 2);
    unsigned short* tweLo = (unsigned short*)alloc((size_t)768 * 128 * 2);
    unsigned short* numHi = (unsigned short*)alloc((size_t)5 * 128 * 2);
    unsigned short* numLo = (unsigned short*)alloc((size_t)5 * 128 * 2);
    unsigned short* catHi = (unsigned short*)alloc((size_t)6 * 128 * 2);
    unsigned short* catLo = (unsigned short*)alloc((size_t)6 * 128 * 2);
    unsigned short* rootHi = (unsigned short*)alloc((size_t)2 * 16384 * 2);
    unsigned short* rootLo = (unsigned short*)alloc((size_t)2 * 16384 * 2);
    unsigned short* relHi  = (unsigned short*)alloc((size_t)4 * 16384 * 2);
    unsigned short* relLo  = (unsigned short*)alloc((size_t)4 * 16384 * 2);
    unsigned short* w1Hi   = (unsigned short*)alloc((size_t)16384 * 2);
    unsigned short* w1Lo   = (unsigned short*)alloc((size_t)16384 * 2);
    float* hf = agg;   // agg is dead once the MLP runs

    // ---- weight prep (tiny) ----
    auto tr = [&](const float* s, unsigned short* dh, unsigned short* dl, int K) {
        const int total = K * 128;
        rg_transpose_split<<<(total + 255) / 256, 256, 0, stream>>>(s, dh, dl, total, K);
    };
    tr(des_w, desHi, desLo, 768);
    tr(twe_w, tweHi, tweLo, 768);
    tr(num_w, numHi, numLo, 5);
    tr(cat_w, catHi, catLo, 6);
    tr(root_w,         rootHi,         rootLo,         128);
    tr(root_w + 16384, rootHi + 16384, rootLo + 16384, 128);
    tr(rel_w + 0 * 16384, relHi + 0 * 16384, relLo + 0 * 16384, 128);
    tr(rel_w + 1 * 16384, relHi + 1 * 16384, relLo + 1 * 16384, 128);
    tr(rel_w + 2 * 16384, relHi + 2 * 16384, relLo + 2 * 16384, 128);
    tr(rel_w + 3 * 16384, relHi + 3 * 16384, relLo + 3 * 16384, 128);
    tr(mlp_w1, w1Hi, w1Lo, 128);

    // ---- edge sort (once; reused by both layers) ----
    hipMemsetAsync(hist, 0, (size_t)NBINS * 4, stream);
    rg_hist<<<(EE + 255) / 256, 256, 0, stream>>>(ei, et, hist);
    rg_scan<<<1, 1024, 0, stream>>>(hist, offs);
    hipMemcpyAsync(cursor, offs, (size_t)NBINS * 4, hipMemcpyDeviceToDevice, stream);
    rg_place<<<(EE + 255) / 256, 256, 0, stream>>>(ei, et, cursor, sorted_src);

    // ---- projection ----
    const int gemm_grid = (NN + 63) / 64;  // 782
    rg_proj<<<gemm_grid, 256, 0, stream>>>(des, twe, num, cat,
                                           desHi, desLo, tweHi, tweLo,
                                           numHi, numLo, catHi, catLo,
                                           des_b, twe_b, num_b, cat_b, xf);

    // ---- RGCN layers: gather-reduce (atomic-free) + fused GEMM ----
    const int gather_grid = (NBINS * 64 + 255) / 256;   // one wave per bin
    for (int l = 0; l < 2; ++l) {
        rg_gather<<<gather_grid, 256, 0, stream>>>(xf, sorted_src, offs, agg);
        rg_gemm<<<gemm_grid, 256, 0, stream>>>(
            xf, agg, agg + (size_t)NN * 128,
            rootHi + (size_t)l * 16384, rootLo + (size_t)l * 16384,
            relHi + (size_t)(l * 2) * 16384, relLo + (size_t)(l * 2) * 16384,
            relHi + (size_t)(l * 2 + 1) * 16384, relLo + (size_t)(l * 2 + 1) * 16384,
            rgcn_b + l * 128, 3, 0, xf);
    }
    // ---- MLP layer 1 (relu) ----
    rg_gemm<<<gemm_grid, 256, 0, stream>>>(xf, nullptr, nullptr,
                                           w1Hi, w1Lo, nullptr, nullptr, nullptr, nullptr,
                                           mlp_b1, 1, 1, hf);
    // ---- head ----
    BotRGCN_64381559767213_kernel<<<2048, 256, 0, stream>>>(hf, mlp_w2, mlp_b2,
                                                            (float*)d_out);
}